// Round 1
// 534.516 us; speedup vs baseline: 1.1715x; 1.1715x over previous
//
#include <hip/hip_runtime.h>

typedef unsigned short u16;
typedef unsigned int u32;
typedef __attribute__((ext_vector_type(8))) short short8;   // 8 bf16 MFMA frag (4 VGPRs)
typedef __attribute__((ext_vector_type(4))) float f32x4;
typedef __attribute__((ext_vector_type(2))) unsigned int u32x2;
typedef __attribute__((ext_vector_type(4))) unsigned int u32x4;

#define BB 4
#define CC 256
#define NT 4096
#define L2E 1.4426950408889634f

__device__ __forceinline__ float b2f(u16 v) {
    union { u32 u; float f; } c; c.u = ((u32)v) << 16; return c.f;
}
__device__ __forceinline__ u16 f2b(float f) {
    union { float f; u32 u; } c; c.f = f;
    u32 u = c.u;
    return (u16)((u + 0x7fffu + ((u >> 16) & 1u)) >> 16);   // RNE
}

// ---------------------------------------------------------------------------
// K1: fused projections (fp32 in). Y = [Wq;Wk;Wv](320x256) @ x(256x4096) per b.
// fp32 VALU GEMM, LDS tiles, 4x4 reg tiling. Emits bf16 MFMA-layout outputs:
//   qh/ql [b][n][32] (Dekker split q=qh+ql), kh/kl [b][m][32], pvw [b][c][n].
// (unchanged this round — will profile next round once kout/kattn shrink)
// ---------------------------------------------------------------------------
__global__ __launch_bounds__(256) void kproj(
    const float* __restrict__ x,
    const float* __restrict__ Wq, const float* __restrict__ bq,
    const float* __restrict__ Wk, const float* __restrict__ bk,
    const float* __restrict__ Wv, const float* __restrict__ bv,
    u16* __restrict__ qh, u16* __restrict__ ql,
    u16* __restrict__ kh, u16* __restrict__ kl,
    u16* __restrict__ pvw)
{
    __shared__ __align__(16) float lA[32][68];   // [k][row]
    __shared__ __align__(16) float lX[32][68];   // [k][col]
    const int mt = blockIdx.x, nt = blockIdx.y, b = blockIdx.z;
    const int t = threadIdx.x;
    const int tx = t & 15, ty = t >> 4;
    const int n0 = nt * 64;

    float acc[4][4];
    #pragma unroll
    for (int i = 0; i < 4; ++i)
        #pragma unroll
        for (int j = 0; j < 4; ++j) acc[i][j] = 0.f;

    const int rA = t >> 2, kqA = (t & 3) * 8;       // A: row rA, k-chunk kqA..+7
    const int rgA = mt * 64 + rA;
    const float* wrow;
    if (rgA < 32)      wrow = Wq + rgA * 256;
    else if (rgA < 64) wrow = Wk + (rgA - 32) * 256;
    else               wrow = Wv + (rgA - 64) * 256;
    const int kX = t >> 3, nn8 = (t & 7) * 8;       // X: k-row kX, col chunk nn8..+7
    const float* xrow = x + ((size_t)(b * CC + kX)) * NT + n0 + nn8;

    for (int k0 = 0; k0 < 256; k0 += 32) {
        f32x4 wa = *(const f32x4*)(wrow + k0 + kqA);
        f32x4 wb = *(const f32x4*)(wrow + k0 + kqA + 4);
        f32x4 xa = *(const f32x4*)(xrow + (size_t)k0 * NT);
        f32x4 xb = *(const f32x4*)(xrow + (size_t)k0 * NT + 4);
        __syncthreads();    // protect previous iteration's LDS reads
        #pragma unroll
        for (int j = 0; j < 4; ++j) {
            lA[kqA + j    ][rA] = wa[j];
            lA[kqA + j + 4][rA] = wb[j];
        }
        *(f32x4*)&lX[kX][nn8]     = xa;
        *(f32x4*)&lX[kX][nn8 + 4] = xb;
        __syncthreads();
        #pragma unroll
        for (int k = 0; k < 32; ++k) {
            f32x4 av  = *(const f32x4*)&lA[k][ty * 4];
            f32x4 xvv = *(const f32x4*)&lX[k][tx * 4];
            #pragma unroll
            for (int i = 0; i < 4; ++i)
                #pragma unroll
                for (int j = 0; j < 4; ++j)
                    acc[i][j] = fmaf(av[i], xvv[j], acc[i][j]);
        }
    }

    #pragma unroll
    for (int i = 0; i < 4; ++i) {
        const int rg = mt * 64 + ty * 4 + i;
        float bias;
        if (rg < 32)      bias = bq[rg];
        else if (rg < 64) bias = bk[rg - 32];
        else              bias = bv[rg - 64];
        #pragma unroll
        for (int j = 0; j < 4; ++j) {
            const int n = n0 + tx * 4 + j;
            const float val = acc[i][j] + bias;
            const u16 h = f2b(val);
            const u16 l = f2b(val - b2f(h));
            if (rg < 32) {
                const size_t idx = ((size_t)(b * NT + n)) * 32 + rg;
                qh[idx] = h; ql[idx] = l;
            } else if (rg < 64) {
                const size_t idx = ((size_t)(b * NT + n)) * 32 + (rg - 32);
                kh[idx] = h; kl[idx] = l;
            } else {
                pvw[((size_t)b * CC + (rg - 64)) * NT + n] = f2b(val);
            }
        }
    }
}

// ---------------------------------------------------------------------------
// K2: energy + masked renormalized softmax -> sa (fp32, into d_out).
// sa[n,m] = v[m]*exp(e[n,m]) / sum_m v[m]*exp(e[n,m])  (softmax Z cancels).
// e via 3 MFMAs (qh*kh + ql*kh + qh*kl) for ~2^-18 dot error.
// v2: block = 4 waves sharing the SAME 16 rows, each wave owns 64 of the 256
// ct-chunks (column split). Partial row-sums reduced across waves via LDS.
// Grid 256x4 -> 16 waves/CU (was 4): 4x latency hiding.
// ---------------------------------------------------------------------------
__global__ __launch_bounds__(256) void kattn(
    const u16* __restrict__ qh, const u16* __restrict__ ql,
    const u16* __restrict__ kh, const u16* __restrict__ kl,
    const float* __restrict__ valid, float* __restrict__ sa)
{
    __shared__ float sred[4][4][4];          // [wave][quad][i]
    const int b    = blockIdx.y;
    const int lane = threadIdx.x & 63;
    const int wv   = threadIdx.x >> 6;       // ct-split index 0..3
    const int r0   = blockIdx.x * 16;        // 16 q-rows per block
    const int quad = lane >> 4, l16 = lane & 15;
    const int ct0  = wv * 64;

    const size_t abase = ((size_t)(b * NT + r0 + l16)) * 32 + quad * 8;
    const short8 aqh = *(const short8*)(qh + abase);
    const short8 aql = *(const short8*)(ql + abase);
    const size_t kb = (size_t)b * NT * 32 + (size_t)l16 * 32 + quad * 8;
    const float* vb = valid + b * NT + l16;
    const f32x4 zero = {0.f, 0.f, 0.f, 0.f};

    float sacc[4] = {0.f, 0.f, 0.f, 0.f};
    for (int ct = ct0; ct < ct0 + 64; ++ct) {
        short8 bh = *(const short8*)(kh + kb + (size_t)ct * 512);
        short8 bl = *(const short8*)(kl + kb + (size_t)ct * 512);
        float vcol = vb[ct * 16];
        f32x4 d = __builtin_amdgcn_mfma_f32_16x16x32_bf16(aqh, bh, zero, 0, 0, 0);
        d = __builtin_amdgcn_mfma_f32_16x16x32_bf16(aql, bh, d, 0, 0, 0);
        d = __builtin_amdgcn_mfma_f32_16x16x32_bf16(aqh, bl, d, 0, 0, 0);
        #pragma unroll
        for (int i = 0; i < 4; ++i)
            sacc[i] += vcol * exp2f(fminf(d[i], 60.f) * L2E);
    }
    #pragma unroll
    for (int i = 0; i < 4; ++i) {
        #pragma unroll
        for (int off = 1; off < 16; off <<= 1)
            sacc[i] += __shfl_xor(sacc[i], off, 64);
    }
    if (l16 == 0) {
        #pragma unroll
        for (int i = 0; i < 4; ++i) sred[wv][quad][i] = sacc[i];
    }
    __syncthreads();
    float inv[4];
    #pragma unroll
    for (int i = 0; i < 4; ++i)
        inv[i] = 1.0f / (sred[0][quad][i] + sred[1][quad][i] +
                         sred[2][quad][i] + sred[3][quad][i]);

    for (int ct = ct0; ct < ct0 + 64; ++ct) {
        short8 bh = *(const short8*)(kh + kb + (size_t)ct * 512);
        short8 bl = *(const short8*)(kl + kb + (size_t)ct * 512);
        float vcol = vb[ct * 16];
        f32x4 d = __builtin_amdgcn_mfma_f32_16x16x32_bf16(aqh, bh, zero, 0, 0, 0);
        d = __builtin_amdgcn_mfma_f32_16x16x32_bf16(aql, bh, d, 0, 0, 0);
        d = __builtin_amdgcn_mfma_f32_16x16x32_bf16(aqh, bl, d, 0, 0, 0);
        #pragma unroll
        for (int i = 0; i < 4; ++i) {
            float val = vcol * exp2f(fminf(d[i], 60.f) * L2E) * inv[i];
            sa[((size_t)(b * NT + r0 + quad * 4 + i)) * NT + ct * 16 + l16] = val;
        }
    }
}

// ---------------------------------------------------------------------------
// K3: out[b,c,m] = gamma * sum_n pv[c,n]*sa[m,n] + x[b,c,m]  (fp32 I/O).
// GEMM M=256(c) x N=4096(m) x K=4096(n). Block = 8 waves = full C x 32 m-cols.
// v2: k-step 128, double-buffered swizzled LDS, reg-staged prefetch one tile
// ahead, raw s_barrier + explicit lgkmcnt(0) (ONE barrier per tile; prefetch
// vmcnt stays in flight across barriers — no __syncthreads vmcnt(0) drain).
// LDS: [2][32 m][128 k] bf16, byte ^= ((row&7)<<4) on write AND read (T2/G4).
// ---------------------------------------------------------------------------
#define KOUT_BODY(CUR, T, NXA, NXB, FTA, FTB)                                  \
  {                                                                            \
    if ((T) + 2 < 32) {                                                        \
      FTA = *(const f32x4*)(sap + (size_t)((T) + 2) * 128);                    \
      FTB = *(const f32x4*)(sap + (size_t)((T) + 2) * 128 + 4);                \
    }                                                                          \
    if ((T) + 1 < 32) {                                                        \
      u32 w0 = (u32)f2b(NXA[0]) | ((u32)f2b(NXA[1]) << 16);                    \
      u32 w1 = (u32)f2b(NXA[2]) | ((u32)f2b(NXA[3]) << 16);                    \
      u32 w2 = (u32)f2b(NXB[0]) | ((u32)f2b(NXB[1]) << 16);                    \
      u32 w3 = (u32)f2b(NXB[2]) | ((u32)f2b(NXB[3]) << 16);                    \
      u32x4 pk = {w0, w1, w2, w3};                                             \
      *(u32x4*)(lbw + ((((T) + 1) & 1) * 8192)) = pk;                          \
    }                                                                          \
    const char* lb = lbr + (CUR) * 8192;                                       \
    _Pragma("unroll")                                                          \
    for (int kk = 0; kk < 128; kk += 32) {                                     \
      short8 a0 = *(const short8*)(a0p + (size_t)(T) * 128 + kk);              \
      short8 a1 = *(const short8*)(a1p + (size_t)(T) * 128 + kk);              \
      const int kby = (((kk + quad * 8) * 2) ^ swz);                           \
      short8 b0 = *(const short8*)(lb + l16 * 256 + kby);                      \
      short8 b1 = *(const short8*)(lb + (16 + l16) * 256 + kby);               \
      acc00 = __builtin_amdgcn_mfma_f32_16x16x32_bf16(a0, b0, acc00, 0, 0, 0); \
      acc01 = __builtin_amdgcn_mfma_f32_16x16x32_bf16(a0, b1, acc01, 0, 0, 0); \
      acc10 = __builtin_amdgcn_mfma_f32_16x16x32_bf16(a1, b0, acc10, 0, 0, 0); \
      acc11 = __builtin_amdgcn_mfma_f32_16x16x32_bf16(a1, b1, acc11, 0, 0, 0); \
    }                                                                          \
    asm volatile("s_waitcnt lgkmcnt(0)" ::: "memory");                         \
    __builtin_amdgcn_sched_barrier(0);                                         \
    __builtin_amdgcn_s_barrier();                                              \
    __builtin_amdgcn_sched_barrier(0);                                         \
  }

__global__ __launch_bounds__(512) void kout(
    const u16* __restrict__ pvw, const float* __restrict__ sa,
    const float* __restrict__ x, const float* __restrict__ gamma,
    float* __restrict__ outp)
{
    __shared__ __align__(16) u16 lB[2][32][128];   // 2 x 8 KB, swizzled
    const int b    = blockIdx.y;
    const int m0   = blockIdx.x * 32;
    const int t    = threadIdx.x;
    const int lane = t & 63;
    const int wv   = t >> 6;
    const int c0   = wv * 32;
    const int quad = lane >> 4, l16 = lane & 15;
    const int swz  = (l16 & 7) << 4;

    const u16* a0p = pvw + ((size_t)(b * CC + c0 + l16)) * NT + quad * 8;
    const u16* a1p = a0p + (size_t)16 * NT;
    // staging: thread t: sa row m0+(t>>4), k-chunk (t&15)*8 (8 fp32 = 32 B)
    const int sm = t >> 4, sk = (t & 15) * 8;
    const float* sap = sa + ((size_t)(b * NT + m0 + sm)) * NT + sk;
    char* lbw = ((char*)&lB[0][0][0]) + sm * 256 + ((sk * 2) ^ ((sm & 7) << 4));
    const char* lbr = (const char*)&lB[0][0][0];

    f32x4 acc00 = {0,0,0,0}, acc01 = {0,0,0,0}, acc10 = {0,0,0,0}, acc11 = {0,0,0,0};

    // prologue: tile0 -> buf0; tile1 loads in flight
    f32x4 pA = *(const f32x4*)(sap);
    f32x4 pB = *(const f32x4*)(sap + 4);
    f32x4 nA = *(const f32x4*)(sap + 128);
    f32x4 nB = *(const f32x4*)(sap + 132);
    {
        u32 w0 = (u32)f2b(pA[0]) | ((u32)f2b(pA[1]) << 16);
        u32 w1 = (u32)f2b(pA[2]) | ((u32)f2b(pA[3]) << 16);
        u32 w2 = (u32)f2b(pB[0]) | ((u32)f2b(pB[1]) << 16);
        u32 w3 = (u32)f2b(pB[2]) | ((u32)f2b(pB[3]) << 16);
        u32x4 pk = {w0, w1, w2, w3};
        *(u32x4*)(lbw) = pk;
    }
    asm volatile("s_waitcnt lgkmcnt(0)" ::: "memory");
    __builtin_amdgcn_sched_barrier(0);
    __builtin_amdgcn_s_barrier();
    __builtin_amdgcn_sched_barrier(0);

    f32x4 fA, fB;
    for (int tt = 0; tt < 32; tt += 2) {
        KOUT_BODY(0, tt,     nA, nB, fA, fB)   // compute tile tt, stage tt+1, load tt+2
        KOUT_BODY(1, tt + 1, fA, fB, nA, nB)   // compute tile tt+1, stage tt+2, load tt+3
    }

    const float g = gamma[0];
    #pragma unroll
    for (int ai = 0; ai < 2; ++ai) {
        #pragma unroll
        for (int bi = 0; bi < 2; ++bi) {
            f32x4 acc = (ai == 0) ? ((bi == 0) ? acc00 : acc01)
                                  : ((bi == 0) ? acc10 : acc11);
            #pragma unroll
            for (int i = 0; i < 4; ++i) {
                const int c = c0 + ai * 16 + quad * 4 + i;
                const int m = m0 + bi * 16 + l16;
                const size_t idx = ((size_t)(b * CC + c)) * NT + m;
                outp[idx] = g * acc[i] + x[idx];
            }
        }
    }
}

extern "C" void kernel_launch(void* const* d_in, const int* in_sizes, int n_in,
                              void* d_out, int out_size, void* d_ws, size_t ws_size,
                              hipStream_t stream)
{
    const float* x     = (const float*)d_in[0];
    const float* valid = (const float*)d_in[1];
    const float* Wq    = (const float*)d_in[2];
    const float* bq    = (const float*)d_in[3];
    const float* Wk    = (const float*)d_in[4];
    const float* bk    = (const float*)d_in[5];
    const float* Wv    = (const float*)d_in[6];
    const float* bv    = (const float*)d_in[7];
    const float* gamma = (const float*)d_in[8];

    float* outp = (float*)d_out;
    float* sa   = outp + (size_t)BB * CC * NT;      // output chunk 1 [B][N][N] fp32

    u16* qh  = (u16*)d_ws;                          // [B][N][32] bf16, 1 MB each
    u16* ql  = qh + (size_t)BB * NT * 32;
    u16* kh  = ql + (size_t)BB * NT * 32;
    u16* kl  = kh + (size_t)BB * NT * 32;
    u16* pvw = kl + (size_t)BB * NT * 32;           // [B][C][N] bf16, 8 MB

    kproj<<<dim3(5, 64, BB), 256, 0, stream>>>(x, Wq, bq, Wk, bk, Wv, bv,
                                               qh, ql, kh, kl, pvw);
    kattn<<<dim3(256, BB), 256, 0, stream>>>(qh, ql, kh, kl, valid, sa);
    kout<<<dim3(128, BB), 512, 0, stream>>>(pvw, sa, x, gamma, outp);
}